// Round 7
// baseline (126.666 us; speedup 1.0000x reference)
//
#include <hip/hip_runtime.h>

#define BB 2
#define CIN 64
#define CQ 32
#define DD 8
#define HH 16
#define WWW 16
#define NN 2048   // D*H*W
#define NHW 256   // H*W
#define COUT 64

#define XPLANE 324          // 18*18 padded plane (conv_out)
#define CI_OUT 8            // ci per block (out conv) -- single stage

// conv_qkv spatial-quad geometry
#define QROWS 18            // 16 + h halo
#define QCOLS 20            // 16 + w halo (2) + pad to 20 for 16B row alignment
#define QPLANE (QROWS * QCOLS)   // 360 floats, 1440 B (16B-aligned)
#define QCI 4               // ci per staging phase

#define NPART 8             // softmax partials
#define LOG2E 1.44269504088896340736f

__device__ __forceinline__ float fast_exp2(float x) {
#if __has_builtin(__builtin_amdgcn_exp2f)
    return __builtin_amdgcn_exp2f(x);    // single v_exp_f32
#else
    return exp2f(x);
#endif
}

// ---- init: qkv bufs <- bias ; out <- x + bias (conv kernels atomically accumulate) ----
__global__ __launch_bounds__(256) void init_kernel(
    const float* __restrict__ bk, const float* __restrict__ bq, const float* __restrict__ bv,
    const float* __restrict__ ba, const float* __restrict__ x,
    float* __restrict__ kout, float* __restrict__ qout, float* __restrict__ vout,
    float* __restrict__ out)
{
    int i = blockIdx.x * 256 + threadIdx.x;   // 0 .. 393215
    if (i < BB * CQ * NN) {
        int co = (i >> 11) & 31;
        kout[i] = bk[co];
        qout[i] = bq[co];
        vout[i] = bv[co];
    } else {
        int j = i - BB * CQ * NN;             // 0 .. 262143
        int co = (j >> 11) & 63;
        out[j] = x[j] + ba[co];
    }
}

// ---- fused k,q,v conv: grid 2b*2dquad*16co2*8cisplit = 512 blocks, 256 threads ----
// Spatial register blocking: each thread computes a w-quad (4 adjacent outputs)
// on one d-plane; block covers 4 d-planes x 256 spatial x 2 co x 3 convs
// (24 accumulators/thread). One 6-float LDS window (b128+b64, aligned via
// 20-float row pitch) feeds 12 FMAs per weight set; weights via wave-uniform
// s_load clustered per-kd (54 words -> 3 lgkm drains/ci hide under 216 FMAs).
// 8 ci staged in two 4-ci phases, register-prefetched.
__global__ __launch_bounds__(256, 2) void conv_qkv_kernel(
    const float* __restrict__ x,
    const float* __restrict__ wk, const float* __restrict__ wq, const float* __restrict__ wv,
    float* __restrict__ kout, float* __restrict__ qout, float* __restrict__ vout)
{
    int bid   = blockIdx.x;
    int split = bid & 7;           // 8 ci per split
    int co2   = (bid >> 3) & 15;
    int dq    = (bid >> 7) & 1;
    int b     = bid >> 8;
    int co0   = co2 << 1;
    int ci0   = split << 3;
    int d0    = dq << 2;           // output planes d0 .. d0+3

    // [ci_loc 0..3][plane p: dd=d0-1+p, 0..5][18 rows][20 cols]
    __shared__ float xl[QCI * 6 * QPLANE];   // 8640 floats = 34560 B

    int tid = threadIdx.x;
    // staging coords (writer)
    int hw = tid >> 4;             // 0..15
    int ww = tid & 15;             // 0..15
    int wr = (hw + 1) * QCOLS + (ww + 1);
    // compute coords (reader): pn = d-plane, h row, wqi w-quad
    int pn  = tid >> 6;            // 0..3
    int rem = tid & 63;
    int h   = rem >> 2;            // 0..15
    int wqi = rem & 3;             // 0..3  -> output cols 4*wqi..4*wqi+3

    const float* xb = x + ((size_t)b * CIN + ci0) * NN;

    // ---- prefetch phase 0 (ci 0..3, valid planes only; invalid stay zero) ----
    float r[QCI * 6];
    #pragma unroll
    for (int p = 0; p < 6; ++p) {
        int dd = d0 - 1 + p;
        if (dd >= 0 && dd < DD) {              // block-uniform
            #pragma unroll
            for (int cl = 0; cl < QCI; ++cl)
                r[cl * 6 + p] = xb[(size_t)cl * NN + dd * NHW + tid];
        }
    }
    for (int i = tid; i < QCI * 6 * QPLANE; i += 256) xl[i] = 0.f;
    __syncthreads();
    #pragma unroll
    for (int p = 0; p < 6; ++p) {
        int dd = d0 - 1 + p;
        if (dd >= 0 && dd < DD) {
            #pragma unroll
            for (int cl = 0; cl < QCI; ++cl)
                xl[cl * 6 * QPLANE + p * QPLANE + wr] = r[cl * 6 + p];
        }
    }

    // accumulators: [set 0..5 = k0,k1,q0,q1,v0,v1][w-quad output 0..3]
    float acc[6][4];
    #pragma unroll
    for (int s = 0; s < 6; ++s)
        #pragma unroll
        for (int o = 0; o < 4; ++o) acc[s][o] = 0.f;

    #pragma unroll 1
    for (int ph = 0; ph < 2; ++ph) {
        __syncthreads();   // staged writes visible
        if (ph == 0) {     // issue next phase's loads; drain at post-compute barrier
            #pragma unroll
            for (int p = 0; p < 6; ++p) {
                int dd = d0 - 1 + p;
                if (dd >= 0 && dd < DD) {
                    #pragma unroll
                    for (int cl = 0; cl < QCI; ++cl)
                        r[cl * 6 + p] = xb[(size_t)(QCI + cl) * NN + dd * NHW + tid];
                }
            }
        }

        #pragma unroll 1
        for (int cl = 0; cl < QCI; ++cl) {
            int ci = ci0 + ph * QCI + cl;
            const float* wk0 = wk + ((size_t)co0 * CIN + ci) * 27;
            const float* wk1 = wk0 + (size_t)CIN * 27;
            const float* wq0 = wq + ((size_t)co0 * CIN + ci) * 27;
            const float* wq1 = wq0 + (size_t)CIN * 27;
            const float* wv0 = wv + ((size_t)co0 * CIN + ci) * 27;
            const float* wv1 = wv0 + (size_t)CIN * 27;
            const float* xp  = xl + cl * 6 * QPLANE + pn * QPLANE + h * QCOLS + wqi * 4;

            #pragma unroll
            for (int kd = 0; kd < 3; ++kd) {
                // per-kd weight cluster: 54 wave-uniform words -> SGPRs
                float ws[6][9];
                #pragma unroll
                for (int j = 0; j < 9; ++j) {
                    int t = kd * 9 + j;
                    ws[0][j] = wk0[t]; ws[1][j] = wk1[t];
                    ws[2][j] = wq0[t]; ws[3][j] = wq1[t];
                    ws[4][j] = wv0[t]; ws[5][j] = wv1[t];
                }
                #pragma unroll
                for (int kh = 0; kh < 3; ++kh) {
                    const float* xr = xp + kd * QPLANE + kh * QCOLS;
                    float4 xa  = *(const float4*)xr;
                    float2 xb2 = *(const float2*)(xr + 4);
                    float xw[6] = {xa.x, xa.y, xa.z, xa.w, xb2.x, xb2.y};
                    #pragma unroll
                    for (int kw = 0; kw < 3; ++kw) {
                        int t = kh * 3 + kw;
                        #pragma unroll
                        for (int o = 0; o < 4; ++o) {
                            float xv = xw[o + kw];
                            acc[0][o] = fmaf(ws[0][t], xv, acc[0][o]);
                            acc[1][o] = fmaf(ws[1][t], xv, acc[1][o]);
                            acc[2][o] = fmaf(ws[2][t], xv, acc[2][o]);
                            acc[3][o] = fmaf(ws[3][t], xv, acc[3][o]);
                            acc[4][o] = fmaf(ws[4][t], xv, acc[4][o]);
                            acc[5][o] = fmaf(ws[5][t], xv, acc[5][o]);
                        }
                    }
                }
            }
        }

        __syncthreads();   // compute done
        if (ph == 0) {
            #pragma unroll
            for (int p = 0; p < 6; ++p) {
                int dd = d0 - 1 + p;
                if (dd >= 0 && dd < DD) {
                    #pragma unroll
                    for (int cl = 0; cl < QCI; ++cl)
                        xl[cl * 6 * QPLANE + p * QPLANE + wr] = r[cl * 6 + p];
                }
            }
        }
    }

    // epilogue: 24 atomics (4 w-quad outputs x 6 sets)
    size_t o0 = ((size_t)b * CQ + co0) * NN + (d0 + pn) * NHW + h * WWW + wqi * 4;
    #pragma unroll
    for (int o = 0; o < 4; ++o) {
        unsafeAtomicAdd(&kout[o0 + o],      acc[0][o]);
        unsafeAtomicAdd(&kout[o0 + NN + o], acc[1][o]);
        unsafeAtomicAdd(&qout[o0 + o],      acc[2][o]);
        unsafeAtomicAdd(&qout[o0 + NN + o], acc[3][o]);
        unsafeAtomicAdd(&vout[o0 + o],      acc[4][o]);
        unsafeAtomicAdd(&vout[o0 + NN + o], acc[5][o]);
    }
}

// ---- partial softmax column stats: grid 32c*4mtile*8nchunk = 1024 blocks ----
__global__ __launch_bounds__(256) void mz_partial_kernel(
    const float* __restrict__ kbuf, const float* __restrict__ qbuf,
    float* __restrict__ pmax, float* __restrict__ psum)
{
    int bid = blockIdx.x;
    int nchunk = bid & 7;
    int mtile  = (bid >> 3) & 3;
    int c      = bid >> 5;

    __shared__ float q0l[256], q1l[256];
    int tid = threadIdx.x;
    int n0 = nchunk * 256;
    if (tid < 64) {
        float4 v = ((const float4*)(qbuf + (size_t)c * NN + n0))[tid];
        v.x *= LOG2E; v.y *= LOG2E; v.z *= LOG2E; v.w *= LOG2E;
        ((float4*)q0l)[tid] = v;
    } else if (tid < 128) {
        float4 v = ((const float4*)(qbuf + (size_t)(CQ + c) * NN + n0))[tid - 64];
        v.x *= LOG2E; v.y *= LOG2E; v.z *= LOG2E; v.w *= LOG2E;
        ((float4*)q1l)[tid - 64] = v;
    }
    __syncthreads();

    int m = mtile * 512 + tid * 2;
    float2 k0 = *(const float2*)(kbuf + (size_t)c * NN + m);
    float2 k1 = *(const float2*)(kbuf + (size_t)(CQ + c) * NN + m);

    const float4* q0v = (const float4*)q0l;
    const float4* q1v = (const float4*)q1l;

    float mxa = -1e30f, mxb = -1e30f;
    #pragma unroll 4
    for (int i = 0; i < 64; ++i) {
        float4 a = q0v[i], b4 = q1v[i];
        float sa0 = fmaf(k0.x, a.x, k1.x * b4.x);
        float sa1 = fmaf(k0.x, a.y, k1.x * b4.y);
        float sa2 = fmaf(k0.x, a.z, k1.x * b4.z);
        float sa3 = fmaf(k0.x, a.w, k1.x * b4.w);
        mxa = fmaxf(mxa, fmaxf(fmaxf(sa0, sa1), fmaxf(sa2, sa3)));
        float sb0 = fmaf(k0.y, a.x, k1.y * b4.x);
        float sb1 = fmaf(k0.y, a.y, k1.y * b4.y);
        float sb2 = fmaf(k0.y, a.z, k1.y * b4.z);
        float sb3 = fmaf(k0.y, a.w, k1.y * b4.w);
        mxb = fmaxf(mxb, fmaxf(fmaxf(sb0, sb1), fmaxf(sb2, sb3)));
    }

    float nma = -mxa, nmb = -mxb;
    float za = 0.f, zb = 0.f;
    #pragma unroll 4
    for (int i = 0; i < 64; ++i) {
        float4 a = q0v[i], b4 = q1v[i];
        za += fast_exp2(fmaf(k0.x, a.x, fmaf(k1.x, b4.x, nma)))
            + fast_exp2(fmaf(k0.x, a.y, fmaf(k1.x, b4.y, nma)))
            + fast_exp2(fmaf(k0.x, a.z, fmaf(k1.x, b4.z, nma)))
            + fast_exp2(fmaf(k0.x, a.w, fmaf(k1.x, b4.w, nma)));
        zb += fast_exp2(fmaf(k0.y, a.x, fmaf(k1.y, b4.x, nmb)))
            + fast_exp2(fmaf(k0.y, a.y, fmaf(k1.y, b4.y, nmb)))
            + fast_exp2(fmaf(k0.y, a.z, fmaf(k1.y, b4.z, nmb)))
            + fast_exp2(fmaf(k0.y, a.w, fmaf(k1.y, b4.w, nmb)));
    }
    size_t o = ((size_t)c * NPART + nchunk) * NN + m;
    float2 rm; rm.x = mxa; rm.y = mxb;
    float2 rz; rz.x = za;  rz.y = zb;
    *(float2*)(pmax + o) = rm;
    *(float2*)(psum + o) = rz;
}

// ---- attention apply partial: grid 32c*4ntile*8mchunk = 1024 blocks ----
__global__ __launch_bounds__(256) void att_partial_kernel(
    const float* __restrict__ kbuf, const float* __restrict__ qbuf,
    const float* __restrict__ vbuf,
    const float* __restrict__ pmax, const float* __restrict__ psum,
    float* __restrict__ parts)
{
    int bid = blockIdx.x;
    int mchunk = bid & 7;
    int ntile  = (bid >> 3) & 3;
    int c      = bid >> 5;

    __shared__ float k0l[256], k1l[256], vz0l[256], vz1l[256], nMl[256];
    int tid = threadIdx.x;
    {
        int m = mchunk * 256 + tid;
        float pj[NPART];
        float M = -1e30f;
        #pragma unroll
        for (int j = 0; j < NPART; ++j) {
            pj[j] = pmax[((size_t)c * NPART + j) * NN + m];
            M = fmaxf(M, pj[j]);
        }
        float z = 0.f;
        #pragma unroll
        for (int j = 0; j < NPART; ++j)
            z += psum[((size_t)c * NPART + j) * NN + m] * fast_exp2(pj[j] - M);
        float rz = 1.f / z;   // z >= 1 always
        k0l[tid]  = kbuf[(size_t)c * NN + m];
        k1l[tid]  = kbuf[(size_t)(CQ + c) * NN + m];
        vz0l[tid] = vbuf[(size_t)c * NN + m] * rz;
        vz1l[tid] = vbuf[(size_t)(CQ + c) * NN + m] * rz;
        nMl[tid]  = -M;
    }
    __syncthreads();

    int n = ntile * 512 + tid * 2;
    float2 q0 = *(const float2*)(qbuf + (size_t)c * NN + n);
    float2 q1 = *(const float2*)(qbuf + (size_t)(CQ + c) * NN + n);
    q0.x *= LOG2E; q0.y *= LOG2E;
    q1.x *= LOG2E; q1.y *= LOG2E;

    const float4* k0v = (const float4*)k0l;
    const float4* k1v = (const float4*)k1l;
    const float4* v0v = (const float4*)vz0l;
    const float4* v1v = (const float4*)vz1l;
    const float4* nMv = (const float4*)nMl;

    float a00 = 0.f, a01 = 0.f;   // b=0: n, n+1
    float a10 = 0.f, a11 = 0.f;   // b=1

    #pragma unroll 2
    for (int i = 0; i < 64; ++i) {
        float4 kk0 = k0v[i], kk1 = k1v[i], w0 = v0v[i], w1 = v1v[i], nm = nMv[i];
        #define ATTS(KX,K1X,W0X,W1X,NMX) { \
            float e0 = fast_exp2(fmaf(q0.x, KX, fmaf(q1.x, K1X, NMX))); \
            float e1 = fast_exp2(fmaf(q0.y, KX, fmaf(q1.y, K1X, NMX))); \
            a00 = fmaf(e0, W0X, a00); a10 = fmaf(e0, W1X, a10); \
            a01 = fmaf(e1, W0X, a01); a11 = fmaf(e1, W1X, a11); }
        ATTS(kk0.x, kk1.x, w0.x, w1.x, nm.x)
        ATTS(kk0.y, kk1.y, w0.y, w1.y, nm.y)
        ATTS(kk0.z, kk1.z, w0.z, w1.z, nm.z)
        ATTS(kk0.w, kk1.w, w0.w, w1.w, nm.w)
        #undef ATTS
    }

    float* dst = parts + (size_t)mchunk * (CQ * NN * BB);
    size_t base = ((size_t)c * NN + n) * BB;
    float4 r0; r0.x = a00; r0.y = a10; r0.z = a01; r0.w = a11;
    *(float4*)(dst + base) = r0;
}

// ---- sum 8 partials -> ybuf: grid 128 blocks ----
__global__ __launch_bounds__(256) void combine_kernel(
    const float* __restrict__ parts, float* __restrict__ ybuf)
{
    int i = blockIdx.x * 256 + threadIdx.x;   // float4 index, 32768 total
    float4 s = ((const float4*)parts)[i];
    #pragma unroll
    for (int j = 1; j < NPART; ++j) {
        float4 p = ((const float4*)(parts + (size_t)j * (CQ * NN * BB)))[i];
        s.x += p.x; s.y += p.y; s.z += p.z; s.w += p.w;
    }
    ((float4*)ybuf)[i] = s;
}

// ---- final conv (32->64): grid 2b*8d*16cog*4cisplit = 1024 blocks ----
__global__ __launch_bounds__(256, 4) void conv_out_kernel(
    const float* __restrict__ ybuf,
    const float* __restrict__ wa,
    float* __restrict__ out)
{
    int bid   = blockIdx.x;
    int split = bid & 3;
    int cog   = (bid >> 2) & 15;
    int d     = (bid >> 6) & 7;
    int b     = bid >> 9;
    int co0   = cog << 2;
    int ci0   = split << 3;   // 8 ci per split

    __shared__ float yl[CI_OUT * 3 * XPLANE];   // 31104 B

    int tid = threadIdx.x;
    int h  = tid >> 4;
    int w  = tid & 15;
    int wr = (h + 1) * 18 + (w + 1);
    int rb = h * 18 + w;

    const float* yb = ybuf + ((size_t)b * CQ + ci0) * NN;

    float r[CI_OUT * 3];
    #pragma unroll
    for (int kd = 0; kd < 3; ++kd) {
        int dd = d + kd - 1;
        bool ok = (dd >= 0) && (dd < DD);
        #pragma unroll
        for (int cc = 0; cc < CI_OUT; ++cc)
            r[cc * 3 + kd] = ok ? yb[(size_t)cc * NN + dd * NHW + tid] : 0.f;
    }
    for (int i = tid; i < CI_OUT * 3 * XPLANE; i += 256) yl[i] = 0.f;
    __syncthreads();
    #pragma unroll
    for (int j = 0; j < CI_OUT * 3; ++j)
        yl[j * XPLANE + wr] = r[j];
    __syncthreads();

    float a0 = 0.f, a1 = 0.f, a2 = 0.f, a3 = 0.f;

    for (int cc = 0; cc < CI_OUT; ++cc) {
        int ci = ci0 + cc;
        const float* w0 = wa + ((size_t)(co0 + 0) * CQ + ci) * 27;
        const float* w1 = wa + ((size_t)(co0 + 1) * CQ + ci) * 27;
        const float* w2 = wa + ((size_t)(co0 + 2) * CQ + ci) * 27;
        const float* w3 = wa + ((size_t)(co0 + 3) * CQ + ci) * 27;
        const float* yp = yl + cc * 3 * XPLANE + rb;
        #pragma unroll
        for (int kd = 0; kd < 3; ++kd) {
            int dd = d + kd - 1;
            if (dd < 0 || dd >= DD) continue;   // block-uniform
            #pragma unroll
            for (int kh = 0; kh < 3; ++kh) {
                #pragma unroll
                for (int kw = 0; kw < 3; ++kw) {
                    float yv = yp[kd * XPLANE + kh * 18 + kw];
                    int t = kd * 9 + kh * 3 + kw;
                    a0 = fmaf(yv, w0[t], a0);
                    a1 = fmaf(yv, w1[t], a1);
                    a2 = fmaf(yv, w2[t], a2);
                    a3 = fmaf(yv, w3[t], a3);
                }
            }
        }
    }

    size_t o = ((size_t)b * COUT + co0) * NN + d * NHW + tid;
    unsafeAtomicAdd(&out[o],          a0);
    unsafeAtomicAdd(&out[o + NN],     a1);
    unsafeAtomicAdd(&out[o + 2 * NN], a2);
    unsafeAtomicAdd(&out[o + 3 * NN], a3);
}

extern "C" void kernel_launch(void* const* d_in, const int* in_sizes, int n_in,
                              void* d_out, int out_size, void* d_ws, size_t ws_size,
                              hipStream_t stream) {
    const float* x  = (const float*)d_in[0];
    const float* wk = (const float*)d_in[1];
    const float* bk = (const float*)d_in[2];
    const float* wq = (const float*)d_in[3];
    const float* bq = (const float*)d_in[4];
    const float* wv = (const float*)d_in[5];
    const float* bv = (const float*)d_in[6];
    const float* wa = (const float*)d_in[7];
    const float* ba = (const float*)d_in[8];
    float* out = (float*)d_out;

    float* ws   = (float*)d_ws;
    float* kbuf = ws;                        // [2][32][2048]        131072
    float* qbuf = kbuf + BB * CQ * NN;       // [2][32][2048]        131072
    float* vbuf = qbuf + BB * CQ * NN;       // [2][32][2048]        131072
    float* pmax = vbuf + BB * CQ * NN;       // [32][8][2048]        524288
    float* psum = pmax + CQ * NPART * NN;    // [32][8][2048]        524288
    float* parts = psum + CQ * NPART * NN;   // 8 x [32][2048][2]    1048576
    float* ybuf = kbuf;                      // alias: kbuf dead after att

    init_kernel<<<1536, 256, 0, stream>>>(bk, bq, bv, ba, x, kbuf, qbuf, vbuf, out);
    conv_qkv_kernel<<<512, 256, 0, stream>>>(x, wk, wq, wv, kbuf, qbuf, vbuf);
    mz_partial_kernel<<<1024, 256, 0, stream>>>(kbuf, qbuf, pmax, psum);
    att_partial_kernel<<<1024, 256, 0, stream>>>(kbuf, qbuf, vbuf, pmax, psum, parts);
    combine_kernel<<<128, 256, 0, stream>>>(parts, ybuf);
    conv_out_kernel<<<1024, 256, 0, stream>>>(ybuf, wa, out);
}

// Round 8
// 101.952 us; speedup vs baseline: 1.2424x; 1.2424x over previous
//
#include <hip/hip_runtime.h>

#define BB 2
#define CIN 64
#define CQ 32
#define DD 8
#define HH 16
#define WWW 16
#define NN 2048   // D*H*W
#define NHW 256   // H*W
#define COUT 64

#define XPLANE 324          // 18*18 padded plane (conv_out)
#define CI_OUT 8            // ci per block (out conv) -- single stage

// conv_qkv spatial-quad geometry
#define QROWS 18            // 16 + h halo
#define QCOLS 20            // 16 + w halo (2) + pad to 20 for 16B row alignment
#define QPLANE (QROWS * QCOLS)   // 360 floats, 1440 B (16B-aligned)
#define QCI 4               // ci per staging phase

#define NPART 8             // softmax partials
#define LOG2E 1.44269504088896340736f

__device__ __forceinline__ float fast_exp2(float x) {
#if __has_builtin(__builtin_amdgcn_exp2f)
    return __builtin_amdgcn_exp2f(x);    // single v_exp_f32
#else
    return exp2f(x);
#endif
}

// ---- init: qkv bufs <- bias ; out <- x + bias (conv kernels atomically accumulate) ----
__global__ __launch_bounds__(256) void init_kernel(
    const float* __restrict__ bk, const float* __restrict__ bq, const float* __restrict__ bv,
    const float* __restrict__ ba, const float* __restrict__ x,
    float* __restrict__ kout, float* __restrict__ qout, float* __restrict__ vout,
    float* __restrict__ out)
{
    int i = blockIdx.x * 256 + threadIdx.x;   // 0 .. 393215
    if (i < BB * CQ * NN) {
        int co = (i >> 11) & 31;
        kout[i] = bk[co];
        qout[i] = bq[co];
        vout[i] = bv[co];
    } else {
        int j = i - BB * CQ * NN;             // 0 .. 262143
        int co = (j >> 11) & 63;
        out[j] = x[j] + ba[co];
    }
}

// ---- fused k,q,v conv: grid 512 = 4cisplit(HIGH) x {2b,2dq,32co}(LOW) ----
// w-quad register blocking (one 6-float LDS window feeds 12 FMAs/set).
// ci split = 4 (16 ci/block). Split partners share bid%8 -> SAME XCD, so the
// atomically-accumulated output lines stay resident in one L2 (r7 lesson:
// cross-XCD atomic ping-pong caused 32x HBM write amplification).
// Epilogue transposes accs through LDS so each wave's atomic instr covers a
// 256B-contiguous range (conv_out's proven zero-amplification pattern).
__global__ __launch_bounds__(256, 2) void conv_qkv_kernel(
    const float* __restrict__ x,
    const float* __restrict__ wk, const float* __restrict__ wq, const float* __restrict__ wv,
    float* __restrict__ kout, float* __restrict__ qout, float* __restrict__ vout)
{
    int bid   = blockIdx.x;
    int split = bid >> 7;          // HIGH bits: partners differ only here -> same bid%8
    int inner = bid & 127;
    int co    = inner & 31;
    int dq    = (inner >> 5) & 1;
    int b     = inner >> 6;
    int ci0   = split << 4;        // 16 ci per split
    int d0    = dq << 2;           // output planes d0 .. d0+3

    // [ci_loc 0..3][plane p: dd=d0-1+p, 0..5][18 rows][20 cols]
    __shared__ float xl[QCI * 6 * QPLANE];   // 34560 B
    __shared__ float tl[1024];               // 4 KB epilogue transpose buffer

    int tid = threadIdx.x;
    // staging coords (writer)
    int hw = tid >> 4;             // 0..15
    int ww = tid & 15;             // 0..15
    int wr = (hw + 1) * QCOLS + (ww + 1);
    // compute coords (reader): pn = d-plane (== wave id), h row, wqi w-quad
    int pn  = tid >> 6;            // 0..3
    int rem = tid & 63;
    int h   = rem >> 2;            // 0..15
    int wqi = rem & 3;             // 0..3  -> output cols 4*wqi..4*wqi+3

    const float* xb = x + ((size_t)b * CIN + ci0) * NN;

    // ---- prefetch phase 0 (ci 0..3, valid planes only; invalid stay zero) ----
    float r[QCI * 6];
    #pragma unroll
    for (int p = 0; p < 6; ++p) {
        int dd = d0 - 1 + p;
        if (dd >= 0 && dd < DD) {              // block-uniform
            #pragma unroll
            for (int cl = 0; cl < QCI; ++cl)
                r[cl * 6 + p] = xb[(size_t)cl * NN + dd * NHW + tid];
        }
    }
    for (int i = tid; i < QCI * 6 * QPLANE; i += 256) xl[i] = 0.f;
    __syncthreads();
    #pragma unroll
    for (int p = 0; p < 6; ++p) {
        int dd = d0 - 1 + p;
        if (dd >= 0 && dd < DD) {
            #pragma unroll
            for (int cl = 0; cl < QCI; ++cl)
                xl[cl * 6 * QPLANE + p * QPLANE + wr] = r[cl * 6 + p];
        }
    }

    // accumulators: [set 0..2 = k,q,v][w-quad output 0..3]
    float acc[3][4];
    #pragma unroll
    for (int s = 0; s < 3; ++s)
        #pragma unroll
        for (int o = 0; o < 4; ++o) acc[s][o] = 0.f;

    #pragma unroll 1
    for (int ph = 0; ph < 4; ++ph) {
        __syncthreads();   // staged writes visible
        if (ph < 3) {      // issue next phase's loads; written after post-compute barrier
            #pragma unroll
            for (int p = 0; p < 6; ++p) {
                int dd = d0 - 1 + p;
                if (dd >= 0 && dd < DD) {
                    #pragma unroll
                    for (int cl = 0; cl < QCI; ++cl)
                        r[cl * 6 + p] = xb[(size_t)((ph + 1) * QCI + cl) * NN + dd * NHW + tid];
                }
            }
        }

        #pragma unroll 1
        for (int cl = 0; cl < QCI; ++cl) {
            int ci = ci0 + ph * QCI + cl;
            const float* wk0 = wk + ((size_t)co * CIN + ci) * 27;
            const float* wq0 = wq + ((size_t)co * CIN + ci) * 27;
            const float* wv0 = wv + ((size_t)co * CIN + ci) * 27;
            const float* xp  = xl + cl * 6 * QPLANE + pn * QPLANE + h * QCOLS + wqi * 4;

            #pragma unroll
            for (int kd = 0; kd < 3; ++kd) {
                // per-kd weight cluster: 27 wave-uniform words -> SGPRs
                float ws[3][9];
                #pragma unroll
                for (int j = 0; j < 9; ++j) {
                    int t = kd * 9 + j;
                    ws[0][j] = wk0[t]; ws[1][j] = wq0[t]; ws[2][j] = wv0[t];
                }
                #pragma unroll
                for (int kh = 0; kh < 3; ++kh) {
                    const float* xr = xp + kd * QPLANE + kh * QCOLS;
                    float4 xa  = *(const float4*)xr;
                    float2 xb2 = *(const float2*)(xr + 4);
                    float xw[6] = {xa.x, xa.y, xa.z, xa.w, xb2.x, xb2.y};
                    #pragma unroll
                    for (int kw = 0; kw < 3; ++kw) {
                        int t = kh * 3 + kw;
                        #pragma unroll
                        for (int o = 0; o < 4; ++o) {
                            float xv = xw[o + kw];
                            acc[0][o] = fmaf(ws[0][t], xv, acc[0][o]);
                            acc[1][o] = fmaf(ws[1][t], xv, acc[1][o]);
                            acc[2][o] = fmaf(ws[2][t], xv, acc[2][o]);
                        }
                    }
                }
            }
        }

        __syncthreads();   // compute done
        if (ph < 3) {
            #pragma unroll
            for (int p = 0; p < 6; ++p) {
                int dd = d0 - 1 + p;
                if (dd >= 0 && dd < DD) {
                    #pragma unroll
                    for (int cl = 0; cl < QCI; ++cl)
                        xl[cl * 6 * QPLANE + p * QPLANE + wr] = r[cl * 6 + p];
                }
            }
        }
    }

    // ---- epilogue: LDS transpose per set -> contiguous atomic lanes ----
    size_t base = ((size_t)b * CQ + co) * NN + d0 * NHW;
    int wloc = pn * 256 + h * 16 + wqi * 4;
    #define EMIT_SET(S, BUF) { \
        __syncthreads(); \
        float4 f; f.x = acc[S][0]; f.y = acc[S][1]; f.z = acc[S][2]; f.w = acc[S][3]; \
        *(float4*)&tl[wloc] = f; \
        __syncthreads(); \
        unsafeAtomicAdd(&BUF[base + 0 * NHW + tid], tl[tid]); \
        unsafeAtomicAdd(&BUF[base + 1 * NHW + tid], tl[tid + 256]); \
        unsafeAtomicAdd(&BUF[base + 2 * NHW + tid], tl[tid + 512]); \
        unsafeAtomicAdd(&BUF[base + 3 * NHW + tid], tl[tid + 768]); }
    EMIT_SET(0, kout)
    EMIT_SET(1, qout)
    EMIT_SET(2, vout)
    #undef EMIT_SET
}

// ---- partial softmax column stats: grid 32c*4mtile*8nchunk = 1024 blocks ----
__global__ __launch_bounds__(256) void mz_partial_kernel(
    const float* __restrict__ kbuf, const float* __restrict__ qbuf,
    float* __restrict__ pmax, float* __restrict__ psum)
{
    int bid = blockIdx.x;
    int nchunk = bid & 7;
    int mtile  = (bid >> 3) & 3;
    int c      = bid >> 5;

    __shared__ float q0l[256], q1l[256];
    int tid = threadIdx.x;
    int n0 = nchunk * 256;
    if (tid < 64) {
        float4 v = ((const float4*)(qbuf + (size_t)c * NN + n0))[tid];
        v.x *= LOG2E; v.y *= LOG2E; v.z *= LOG2E; v.w *= LOG2E;
        ((float4*)q0l)[tid] = v;
    } else if (tid < 128) {
        float4 v = ((const float4*)(qbuf + (size_t)(CQ + c) * NN + n0))[tid - 64];
        v.x *= LOG2E; v.y *= LOG2E; v.z *= LOG2E; v.w *= LOG2E;
        ((float4*)q1l)[tid - 64] = v;
    }
    __syncthreads();

    int m = mtile * 512 + tid * 2;
    float2 k0 = *(const float2*)(kbuf + (size_t)c * NN + m);
    float2 k1 = *(const float2*)(kbuf + (size_t)(CQ + c) * NN + m);

    const float4* q0v = (const float4*)q0l;
    const float4* q1v = (const float4*)q1l;

    float mxa = -1e30f, mxb = -1e30f;
    #pragma unroll 4
    for (int i = 0; i < 64; ++i) {
        float4 a = q0v[i], b4 = q1v[i];
        float sa0 = fmaf(k0.x, a.x, k1.x * b4.x);
        float sa1 = fmaf(k0.x, a.y, k1.x * b4.y);
        float sa2 = fmaf(k0.x, a.z, k1.x * b4.z);
        float sa3 = fmaf(k0.x, a.w, k1.x * b4.w);
        mxa = fmaxf(mxa, fmaxf(fmaxf(sa0, sa1), fmaxf(sa2, sa3)));
        float sb0 = fmaf(k0.y, a.x, k1.y * b4.x);
        float sb1 = fmaf(k0.y, a.y, k1.y * b4.y);
        float sb2 = fmaf(k0.y, a.z, k1.y * b4.z);
        float sb3 = fmaf(k0.y, a.w, k1.y * b4.w);
        mxb = fmaxf(mxb, fmaxf(fmaxf(sb0, sb1), fmaxf(sb2, sb3)));
    }

    float nma = -mxa, nmb = -mxb;
    float za = 0.f, zb = 0.f;
    #pragma unroll 4
    for (int i = 0; i < 64; ++i) {
        float4 a = q0v[i], b4 = q1v[i];
        za += fast_exp2(fmaf(k0.x, a.x, fmaf(k1.x, b4.x, nma)))
            + fast_exp2(fmaf(k0.x, a.y, fmaf(k1.x, b4.y, nma)))
            + fast_exp2(fmaf(k0.x, a.z, fmaf(k1.x, b4.z, nma)))
            + fast_exp2(fmaf(k0.x, a.w, fmaf(k1.x, b4.w, nma)));
        zb += fast_exp2(fmaf(k0.y, a.x, fmaf(k1.y, b4.x, nmb)))
            + fast_exp2(fmaf(k0.y, a.y, fmaf(k1.y, b4.y, nmb)))
            + fast_exp2(fmaf(k0.y, a.z, fmaf(k1.y, b4.z, nmb)))
            + fast_exp2(fmaf(k0.y, a.w, fmaf(k1.y, b4.w, nmb)));
    }
    size_t o = ((size_t)c * NPART + nchunk) * NN + m;
    float2 rm; rm.x = mxa; rm.y = mxb;
    float2 rz; rz.x = za;  rz.y = zb;
    *(float2*)(pmax + o) = rm;
    *(float2*)(psum + o) = rz;
}

// ---- attention apply partial: grid 32c*4ntile*8mchunk = 1024 blocks ----
__global__ __launch_bounds__(256) void att_partial_kernel(
    const float* __restrict__ kbuf, const float* __restrict__ qbuf,
    const float* __restrict__ vbuf,
    const float* __restrict__ pmax, const float* __restrict__ psum,
    float* __restrict__ parts)
{
    int bid = blockIdx.x;
    int mchunk = bid & 7;
    int ntile  = (bid >> 3) & 3;
    int c      = bid >> 5;

    __shared__ float k0l[256], k1l[256], vz0l[256], vz1l[256], nMl[256];
    int tid = threadIdx.x;
    {
        int m = mchunk * 256 + tid;
        float pj[NPART];
        float M = -1e30f;
        #pragma unroll
        for (int j = 0; j < NPART; ++j) {
            pj[j] = pmax[((size_t)c * NPART + j) * NN + m];
            M = fmaxf(M, pj[j]);
        }
        float z = 0.f;
        #pragma unroll
        for (int j = 0; j < NPART; ++j)
            z += psum[((size_t)c * NPART + j) * NN + m] * fast_exp2(pj[j] - M);
        float rz = 1.f / z;   // z >= 1 always
        k0l[tid]  = kbuf[(size_t)c * NN + m];
        k1l[tid]  = kbuf[(size_t)(CQ + c) * NN + m];
        vz0l[tid] = vbuf[(size_t)c * NN + m] * rz;
        vz1l[tid] = vbuf[(size_t)(CQ + c) * NN + m] * rz;
        nMl[tid]  = -M;
    }
    __syncthreads();

    int n = ntile * 512 + tid * 2;
    float2 q0 = *(const float2*)(qbuf + (size_t)c * NN + n);
    float2 q1 = *(const float2*)(qbuf + (size_t)(CQ + c) * NN + n);
    q0.x *= LOG2E; q0.y *= LOG2E;
    q1.x *= LOG2E; q1.y *= LOG2E;

    const float4* k0v = (const float4*)k0l;
    const float4* k1v = (const float4*)k1l;
    const float4* v0v = (const float4*)vz0l;
    const float4* v1v = (const float4*)vz1l;
    const float4* nMv = (const float4*)nMl;

    float a00 = 0.f, a01 = 0.f;   // b=0: n, n+1
    float a10 = 0.f, a11 = 0.f;   // b=1

    #pragma unroll 2
    for (int i = 0; i < 64; ++i) {
        float4 kk0 = k0v[i], kk1 = k1v[i], w0 = v0v[i], w1 = v1v[i], nm = nMv[i];
        #define ATTS(KX,K1X,W0X,W1X,NMX) { \
            float e0 = fast_exp2(fmaf(q0.x, KX, fmaf(q1.x, K1X, NMX))); \
            float e1 = fast_exp2(fmaf(q0.y, KX, fmaf(q1.y, K1X, NMX))); \
            a00 = fmaf(e0, W0X, a00); a10 = fmaf(e0, W1X, a10); \
            a01 = fmaf(e1, W0X, a01); a11 = fmaf(e1, W1X, a11); }
        ATTS(kk0.x, kk1.x, w0.x, w1.x, nm.x)
        ATTS(kk0.y, kk1.y, w0.y, w1.y, nm.y)
        ATTS(kk0.z, kk1.z, w0.z, w1.z, nm.z)
        ATTS(kk0.w, kk1.w, w0.w, w1.w, nm.w)
        #undef ATTS
    }

    float* dst = parts + (size_t)mchunk * (CQ * NN * BB);
    size_t base = ((size_t)c * NN + n) * BB;
    float4 r0; r0.x = a00; r0.y = a10; r0.z = a01; r0.w = a11;
    *(float4*)(dst + base) = r0;
}

// ---- sum 8 partials -> ybuf: grid 128 blocks ----
__global__ __launch_bounds__(256) void combine_kernel(
    const float* __restrict__ parts, float* __restrict__ ybuf)
{
    int i = blockIdx.x * 256 + threadIdx.x;   // float4 index, 32768 total
    float4 s = ((const float4*)parts)[i];
    #pragma unroll
    for (int j = 1; j < NPART; ++j) {
        float4 p = ((const float4*)(parts + (size_t)j * (CQ * NN * BB)))[i];
        s.x += p.x; s.y += p.y; s.z += p.z; s.w += p.w;
    }
    ((float4*)ybuf)[i] = s;
}

// ---- final conv (32->64): grid 2b*8d*16cog*4cisplit = 1024 blocks ----
__global__ __launch_bounds__(256, 4) void conv_out_kernel(
    const float* __restrict__ ybuf,
    const float* __restrict__ wa,
    float* __restrict__ out)
{
    int bid   = blockIdx.x;
    int split = bid & 3;
    int cog   = (bid >> 2) & 15;
    int d     = (bid >> 6) & 7;
    int b     = bid >> 9;
    int co0   = cog << 2;
    int ci0   = split << 3;   // 8 ci per split

    __shared__ float yl[CI_OUT * 3 * XPLANE];   // 31104 B

    int tid = threadIdx.x;
    int h  = tid >> 4;
    int w  = tid & 15;
    int wr = (h + 1) * 18 + (w + 1);
    int rb = h * 18 + w;

    const float* yb = ybuf + ((size_t)b * CQ + ci0) * NN;

    float r[CI_OUT * 3];
    #pragma unroll
    for (int kd = 0; kd < 3; ++kd) {
        int dd = d + kd - 1;
        bool ok = (dd >= 0) && (dd < DD);
        #pragma unroll
        for (int cc = 0; cc < CI_OUT; ++cc)
            r[cc * 3 + kd] = ok ? yb[(size_t)cc * NN + dd * NHW + tid] : 0.f;
    }
    for (int i = tid; i < CI_OUT * 3 * XPLANE; i += 256) yl[i] = 0.f;
    __syncthreads();
    #pragma unroll
    for (int j = 0; j < CI_OUT * 3; ++j)
        yl[j * XPLANE + wr] = r[j];
    __syncthreads();

    float a0 = 0.f, a1 = 0.f, a2 = 0.f, a3 = 0.f;

    for (int cc = 0; cc < CI_OUT; ++cc) {
        int ci = ci0 + cc;
        const float* w0 = wa + ((size_t)(co0 + 0) * CQ + ci) * 27;
        const float* w1 = wa + ((size_t)(co0 + 1) * CQ + ci) * 27;
        const float* w2 = wa + ((size_t)(co0 + 2) * CQ + ci) * 27;
        const float* w3 = wa + ((size_t)(co0 + 3) * CQ + ci) * 27;
        const float* yp = yl + cc * 3 * XPLANE + rb;
        #pragma unroll
        for (int kd = 0; kd < 3; ++kd) {
            int dd = d + kd - 1;
            if (dd < 0 || dd >= DD) continue;   // block-uniform
            #pragma unroll
            for (int kh = 0; kh < 3; ++kh) {
                #pragma unroll
                for (int kw = 0; kw < 3; ++kw) {
                    float yv = yp[kd * XPLANE + kh * 18 + kw];
                    int t = kd * 9 + kh * 3 + kw;
                    a0 = fmaf(yv, w0[t], a0);
                    a1 = fmaf(yv, w1[t], a1);
                    a2 = fmaf(yv, w2[t], a2);
                    a3 = fmaf(yv, w3[t], a3);
                }
            }
        }
    }

    size_t o = ((size_t)b * COUT + co0) * NN + d * NHW + tid;
    unsafeAtomicAdd(&out[o],          a0);
    unsafeAtomicAdd(&out[o + NN],     a1);
    unsafeAtomicAdd(&out[o + 2 * NN], a2);
    unsafeAtomicAdd(&out[o + 3 * NN], a3);
}

extern "C" void kernel_launch(void* const* d_in, const int* in_sizes, int n_in,
                              void* d_out, int out_size, void* d_ws, size_t ws_size,
                              hipStream_t stream) {
    const float* x  = (const float*)d_in[0];
    const float* wk = (const float*)d_in[1];
    const float* bk = (const float*)d_in[2];
    const float* wq = (const float*)d_in[3];
    const float* bq = (const float*)d_in[4];
    const float* wv = (const float*)d_in[5];
    const float* bv = (const float*)d_in[6];
    const float* wa = (const float*)d_in[7];
    const float* ba = (const float*)d_in[8];
    float* out = (float*)d_out;

    float* ws   = (float*)d_ws;
    float* kbuf = ws;                        // [2][32][2048]        131072
    float* qbuf = kbuf + BB * CQ * NN;       // [2][32][2048]        131072
    float* vbuf = qbuf + BB * CQ * NN;       // [2][32][2048]        131072
    float* pmax = vbuf + BB * CQ * NN;       // [32][8][2048]        524288
    float* psum = pmax + CQ * NPART * NN;    // [32][8][2048]        524288
    float* parts = psum + CQ * NPART * NN;   // 8 x [32][2048][2]    1048576
    float* ybuf = kbuf;                      // alias: kbuf dead after att

    init_kernel<<<1536, 256, 0, stream>>>(bk, bq, bv, ba, x, kbuf, qbuf, vbuf, out);
    conv_qkv_kernel<<<512, 256, 0, stream>>>(x, wk, wq, wv, kbuf, qbuf, vbuf);
    mz_partial_kernel<<<1024, 256, 0, stream>>>(kbuf, qbuf, pmax, psum);
    att_partial_kernel<<<1024, 256, 0, stream>>>(kbuf, qbuf, vbuf, pmax, psum, parts);
    combine_kernel<<<128, 256, 0, stream>>>(parts, ybuf);
    conv_out_kernel<<<1024, 256, 0, stream>>>(ybuf, wa, out);
}

// Round 9
// 96.626 us; speedup vs baseline: 1.3109x; 1.0551x over previous
//
#include <hip/hip_runtime.h>

#define BB 2
#define CIN 64
#define CQ 32
#define DD 8
#define HH 16
#define WWW 16
#define NN 2048   // D*H*W
#define NHW 256   // H*W
#define COUT 64

#define XPLANE 324          // 18*18 padded plane (conv_out)
#define CI_OUT 8            // ci per block (out conv) -- single stage

// conv_qkv spatial-quad geometry
#define QROWS 18
#define QCOLS 20
#define QPLANE (QROWS * QCOLS)   // 360 floats
#define QCI 4               // ci per staging phase

#define LOG2E 1.44269504088896340736f

__device__ __forceinline__ float fast_exp2(float x) {
#if __has_builtin(__builtin_amdgcn_exp2f)
    return __builtin_amdgcn_exp2f(x);    // single v_exp_f32
#else
    return exp2f(x);
#endif
}

// ---- init: qkv <- bias ; out <- x + bias ; zbuf,ybuf <- 0 ----
// grid 2304 x 256 covers 131072 (kqv) + 262144 (out) + 65536 (z) + 131072 (y)
__global__ __launch_bounds__(256) void init_kernel(
    const float* __restrict__ bk, const float* __restrict__ bq, const float* __restrict__ bv,
    const float* __restrict__ ba, const float* __restrict__ x,
    float* __restrict__ kout, float* __restrict__ qout, float* __restrict__ vout,
    float* __restrict__ out, float* __restrict__ zbuf, float* __restrict__ ybuf)
{
    int i = blockIdx.x * 256 + threadIdx.x;
    if (i < BB * CQ * NN) {
        int co = (i >> 11) & 31;
        kout[i] = bk[co];
        qout[i] = bq[co];
        vout[i] = bv[co];
    } else if (i < 3 * BB * CQ * NN) {
        int j = i - BB * CQ * NN;             // 0 .. 262143
        int co = (j >> 11) & 63;
        out[j] = x[j] + ba[co];
    } else if (i < 3 * BB * CQ * NN + CQ * NN) {
        zbuf[i - 3 * BB * CQ * NN] = 0.f;
    } else {
        ybuf[i - 3 * BB * CQ * NN - CQ * NN] = 0.f;
    }
}

// ---- fused k,q,v conv: grid 512 = 4cisplit(HIGH) x {2b,2dq,32co}(LOW) ----
// (r8-proven structure; epilogue barriers merged: one LDS transpose for all 3 sets)
__global__ __launch_bounds__(256, 2) void conv_qkv_kernel(
    const float* __restrict__ x,
    const float* __restrict__ wk, const float* __restrict__ wq, const float* __restrict__ wv,
    float* __restrict__ kout, float* __restrict__ qout, float* __restrict__ vout)
{
    int bid   = blockIdx.x;
    int split = bid >> 7;          // HIGH bits: split partners share bid%8 -> same XCD
    int inner = bid & 127;
    int co    = inner & 31;
    int dq    = (inner >> 5) & 1;
    int b     = inner >> 6;
    int ci0   = split << 4;        // 16 ci per split
    int d0    = dq << 2;           // output planes d0 .. d0+3

    __shared__ float xl[QCI * 6 * QPLANE];   // 34560 B
    __shared__ float tl[3 * 1024];           // 12 KB epilogue transpose buffer

    int tid = threadIdx.x;
    int hw = tid >> 4;
    int ww = tid & 15;
    int wr = (hw + 1) * QCOLS + (ww + 1);
    int pn  = tid >> 6;            // 0..3 d-plane
    int rem = tid & 63;
    int h   = rem >> 2;            // 0..15
    int wqi = rem & 3;             // 0..3

    const float* xb = x + ((size_t)b * CIN + ci0) * NN;

    float r[QCI * 6];
    #pragma unroll
    for (int p = 0; p < 6; ++p) {
        int dd = d0 - 1 + p;
        if (dd >= 0 && dd < DD) {              // block-uniform
            #pragma unroll
            for (int cl = 0; cl < QCI; ++cl)
                r[cl * 6 + p] = xb[(size_t)cl * NN + dd * NHW + tid];
        }
    }
    for (int i = tid; i < QCI * 6 * QPLANE; i += 256) xl[i] = 0.f;
    __syncthreads();
    #pragma unroll
    for (int p = 0; p < 6; ++p) {
        int dd = d0 - 1 + p;
        if (dd >= 0 && dd < DD) {
            #pragma unroll
            for (int cl = 0; cl < QCI; ++cl)
                xl[cl * 6 * QPLANE + p * QPLANE + wr] = r[cl * 6 + p];
        }
    }

    float acc[3][4];
    #pragma unroll
    for (int s = 0; s < 3; ++s)
        #pragma unroll
        for (int o = 0; o < 4; ++o) acc[s][o] = 0.f;

    #pragma unroll 1
    for (int ph = 0; ph < 4; ++ph) {
        __syncthreads();
        if (ph < 3) {
            #pragma unroll
            for (int p = 0; p < 6; ++p) {
                int dd = d0 - 1 + p;
                if (dd >= 0 && dd < DD) {
                    #pragma unroll
                    for (int cl = 0; cl < QCI; ++cl)
                        r[cl * 6 + p] = xb[(size_t)((ph + 1) * QCI + cl) * NN + dd * NHW + tid];
                }
            }
        }

        #pragma unroll 1
        for (int cl = 0; cl < QCI; ++cl) {
            int ci = ci0 + ph * QCI + cl;
            const float* wk0 = wk + ((size_t)co * CIN + ci) * 27;
            const float* wq0 = wq + ((size_t)co * CIN + ci) * 27;
            const float* wv0 = wv + ((size_t)co * CIN + ci) * 27;
            const float* xp  = xl + cl * 6 * QPLANE + pn * QPLANE + h * QCOLS + wqi * 4;

            #pragma unroll
            for (int kd = 0; kd < 3; ++kd) {
                float ws[3][9];
                #pragma unroll
                for (int j = 0; j < 9; ++j) {
                    int t = kd * 9 + j;
                    ws[0][j] = wk0[t]; ws[1][j] = wq0[t]; ws[2][j] = wv0[t];
                }
                #pragma unroll
                for (int kh = 0; kh < 3; ++kh) {
                    const float* xr = xp + kd * QPLANE + kh * QCOLS;
                    float4 xa  = *(const float4*)xr;
                    float2 xb2 = *(const float2*)(xr + 4);
                    float xw[6] = {xa.x, xa.y, xa.z, xa.w, xb2.x, xb2.y};
                    #pragma unroll
                    for (int kw = 0; kw < 3; ++kw) {
                        int t = kh * 3 + kw;
                        #pragma unroll
                        for (int o = 0; o < 4; ++o) {
                            float xv = xw[o + kw];
                            acc[0][o] = fmaf(ws[0][t], xv, acc[0][o]);
                            acc[1][o] = fmaf(ws[1][t], xv, acc[1][o]);
                            acc[2][o] = fmaf(ws[2][t], xv, acc[2][o]);
                        }
                    }
                }
            }
        }

        __syncthreads();
        if (ph < 3) {
            #pragma unroll
            for (int p = 0; p < 6; ++p) {
                int dd = d0 - 1 + p;
                if (dd >= 0 && dd < DD) {
                    #pragma unroll
                    for (int cl = 0; cl < QCI; ++cl)
                        xl[cl * 6 * QPLANE + p * QPLANE + wr] = r[cl * 6 + p];
                }
            }
        }
    }

    // ---- epilogue: one LDS transpose (all 3 sets) -> contiguous atomic lanes ----
    size_t base = ((size_t)b * CQ + co) * NN + d0 * NHW;
    int wloc = pn * 256 + h * 16 + wqi * 4;
    __syncthreads();
    {
        float4 f0; f0.x = acc[0][0]; f0.y = acc[0][1]; f0.z = acc[0][2]; f0.w = acc[0][3];
        float4 f1; f1.x = acc[1][0]; f1.y = acc[1][1]; f1.z = acc[1][2]; f1.w = acc[1][3];
        float4 f2; f2.x = acc[2][0]; f2.y = acc[2][1]; f2.z = acc[2][2]; f2.w = acc[2][3];
        *(float4*)&tl[wloc]        = f0;
        *(float4*)&tl[1024 + wloc] = f1;
        *(float4*)&tl[2048 + wloc] = f2;
    }
    __syncthreads();
    #pragma unroll
    for (int p = 0; p < 4; ++p) {
        unsafeAtomicAdd(&kout[base + p * NHW + tid], tl[p * 256 + tid]);
        unsafeAtomicAdd(&qout[base + p * NHW + tid], tl[1024 + p * 256 + tid]);
        unsafeAtomicAdd(&vout[base + p * NHW + tid], tl[2048 + p * 256 + tid]);
    }
}

// ---- per-(b,c) row max|q|: grid 64 x 256 ----
__global__ __launch_bounds__(256) void qmax_kernel(
    const float* __restrict__ qbuf, float* __restrict__ mq)
{
    int row = blockIdx.x;          // b*32 + c layout matches qbuf rows
    int tid = threadIdx.x;
    const float4* q = (const float4*)(qbuf + (size_t)row * NN);
    float4 v0 = q[tid], v1 = q[tid + 256];
    float mx = fmaxf(fmaxf(fmaxf(fabsf(v0.x), fabsf(v0.y)), fmaxf(fabsf(v0.z), fabsf(v0.w))),
                     fmaxf(fmaxf(fabsf(v1.x), fabsf(v1.y)), fmaxf(fabsf(v1.z), fabsf(v1.w))));
    #pragma unroll
    for (int off = 32; off; off >>= 1)
        mx = fmaxf(mx, __shfl_down(mx, off, 64));
    __shared__ float red[4];
    if ((tid & 63) == 0) red[tid >> 6] = mx;
    __syncthreads();
    if (tid == 0) mq[row] = fmaxf(fmaxf(red[0], red[1]), fmaxf(red[2], red[3]));
}

// ---- softmax denominators with upper-bound shift: grid 1024 ----
// bid = nchunk(HIGH)*128 + c*4 + mtile  -> 8 nchunk partners co-XCD for zbuf atomics.
// M_ub[m] = |k0[m]|*mq0 + |k1[m]|*mq1 >= S[n,m] for all n (no max pass needed).
// zbuf[c][m] += sum_n exp2(LOG2E*(S - M_ub)).
__global__ __launch_bounds__(256) void mz_partial_kernel(
    const float* __restrict__ kbuf, const float* __restrict__ qbuf,
    const float* __restrict__ mq, float* __restrict__ zbuf)
{
    int bid = blockIdx.x;
    int nchunk = bid >> 7;
    int c      = (bid >> 2) & 31;
    int mtile  = bid & 3;

    __shared__ float q0l[256], q1l[256];
    int tid = threadIdx.x;
    int n0 = nchunk * 256;
    if (tid < 64) {
        float4 v = ((const float4*)(qbuf + (size_t)c * NN + n0))[tid];
        v.x *= LOG2E; v.y *= LOG2E; v.z *= LOG2E; v.w *= LOG2E;
        ((float4*)q0l)[tid] = v;
    } else if (tid < 128) {
        float4 v = ((const float4*)(qbuf + (size_t)(CQ + c) * NN + n0))[tid - 64];
        v.x *= LOG2E; v.y *= LOG2E; v.z *= LOG2E; v.w *= LOG2E;
        ((float4*)q1l)[tid - 64] = v;
    }
    __syncthreads();

    int m = mtile * 512 + tid * 2;
    float2 k0 = *(const float2*)(kbuf + (size_t)c * NN + m);
    float2 k1 = *(const float2*)(kbuf + (size_t)(CQ + c) * NN + m);
    float mq0 = mq[c], mq1 = mq[CQ + c];

    float nma = -LOG2E * fmaf(fabsf(k0.x), mq0, fabsf(k1.x) * mq1);
    float nmb = -LOG2E * fmaf(fabsf(k0.y), mq0, fabsf(k1.y) * mq1);

    const float4* q0v = (const float4*)q0l;
    const float4* q1v = (const float4*)q1l;

    float za = 0.f, zb = 0.f;
    #pragma unroll 4
    for (int i = 0; i < 64; ++i) {
        float4 a = q0v[i], b4 = q1v[i];
        za += fast_exp2(fmaf(k0.x, a.x, fmaf(k1.x, b4.x, nma)))
            + fast_exp2(fmaf(k0.x, a.y, fmaf(k1.x, b4.y, nma)))
            + fast_exp2(fmaf(k0.x, a.z, fmaf(k1.x, b4.z, nma)))
            + fast_exp2(fmaf(k0.x, a.w, fmaf(k1.x, b4.w, nma)));
        zb += fast_exp2(fmaf(k0.y, a.x, fmaf(k1.y, b4.x, nmb)))
            + fast_exp2(fmaf(k0.y, a.y, fmaf(k1.y, b4.y, nmb)))
            + fast_exp2(fmaf(k0.y, a.z, fmaf(k1.y, b4.z, nmb)))
            + fast_exp2(fmaf(k0.y, a.w, fmaf(k1.y, b4.w, nmb)));
    }
    unsafeAtomicAdd(&zbuf[(size_t)c * NN + m],     za);
    unsafeAtomicAdd(&zbuf[(size_t)c * NN + m + 1], zb);
}

// ---- attention apply, accumulating directly into ybuf: grid 1024 ----
// bid = mchunk(HIGH)*128 + c*4 + ntile -> 8 mchunk partners co-XCD for ybuf atomics.
__global__ __launch_bounds__(256) void att_partial_kernel(
    const float* __restrict__ kbuf, const float* __restrict__ qbuf,
    const float* __restrict__ vbuf,
    const float* __restrict__ mq, const float* __restrict__ zbuf,
    float* __restrict__ ybuf)
{
    int bid = blockIdx.x;
    int mchunk = bid >> 7;
    int c      = (bid >> 2) & 31;
    int ntile  = bid & 3;

    __shared__ float k0l[256], k1l[256], vz0l[256], vz1l[256], nMl[256];
    int tid = threadIdx.x;
    {
        int m = mchunk * 256 + tid;
        float k0 = kbuf[(size_t)c * NN + m];
        float k1 = kbuf[(size_t)(CQ + c) * NN + m];
        float mq0 = mq[c], mq1 = mq[CQ + c];
        float rz = 1.f / zbuf[(size_t)c * NN + m];
        k0l[tid]  = k0;
        k1l[tid]  = k1;
        vz0l[tid] = vbuf[(size_t)c * NN + m] * rz;
        vz1l[tid] = vbuf[(size_t)(CQ + c) * NN + m] * rz;
        nMl[tid]  = -LOG2E * fmaf(fabsf(k0), mq0, fabsf(k1) * mq1);
    }
    __syncthreads();

    int n = ntile * 512 + tid * 2;
    float2 q0 = *(const float2*)(qbuf + (size_t)c * NN + n);
    float2 q1 = *(const float2*)(qbuf + (size_t)(CQ + c) * NN + n);
    q0.x *= LOG2E; q0.y *= LOG2E;
    q1.x *= LOG2E; q1.y *= LOG2E;

    const float4* k0v = (const float4*)k0l;
    const float4* k1v = (const float4*)k1l;
    const float4* v0v = (const float4*)vz0l;
    const float4* v1v = (const float4*)vz1l;
    const float4* nMv = (const float4*)nMl;

    float a00 = 0.f, a01 = 0.f;   // b=0: n, n+1
    float a10 = 0.f, a11 = 0.f;   // b=1

    #pragma unroll 2
    for (int i = 0; i < 64; ++i) {
        float4 kk0 = k0v[i], kk1 = k1v[i], w0 = v0v[i], w1 = v1v[i], nm = nMv[i];
        #define ATTS(KX,K1X,W0X,W1X,NMX) { \
            float e0 = fast_exp2(fmaf(q0.x, KX, fmaf(q1.x, K1X, NMX))); \
            float e1 = fast_exp2(fmaf(q0.y, KX, fmaf(q1.y, K1X, NMX))); \
            a00 = fmaf(e0, W0X, a00); a10 = fmaf(e0, W1X, a10); \
            a01 = fmaf(e1, W0X, a01); a11 = fmaf(e1, W1X, a11); }
        ATTS(kk0.x, kk1.x, w0.x, w1.x, nm.x)
        ATTS(kk0.y, kk1.y, w0.y, w1.y, nm.y)
        ATTS(kk0.z, kk1.z, w0.z, w1.z, nm.z)
        ATTS(kk0.w, kk1.w, w0.w, w1.w, nm.w)
        #undef ATTS
    }

    size_t base = ((size_t)c * NN + n) * BB;   // ybuf flat [c][n][b]
    unsafeAtomicAdd(&ybuf[base + 0], a00);
    unsafeAtomicAdd(&ybuf[base + 1], a10);
    unsafeAtomicAdd(&ybuf[base + 2], a01);
    unsafeAtomicAdd(&ybuf[base + 3], a11);
}

// ---- final conv (32->64): grid 2b*8d*16cog*4cisplit = 1024 blocks ----
__global__ __launch_bounds__(256, 4) void conv_out_kernel(
    const float* __restrict__ ybuf,
    const float* __restrict__ wa,
    float* __restrict__ out)
{
    int bid   = blockIdx.x;
    int split = bid & 3;
    int cog   = (bid >> 2) & 15;
    int d     = (bid >> 6) & 7;
    int b     = bid >> 9;
    int co0   = cog << 2;
    int ci0   = split << 3;   // 8 ci per split

    __shared__ float yl[CI_OUT * 3 * XPLANE];   // 31104 B

    int tid = threadIdx.x;
    int h  = tid >> 4;
    int w  = tid & 15;
    int wr = (h + 1) * 18 + (w + 1);
    int rb = h * 18 + w;

    const float* yb = ybuf + ((size_t)b * CQ + ci0) * NN;   // [C,N,B] flat as [B][32][2048]

    float r[CI_OUT * 3];
    #pragma unroll
    for (int kd = 0; kd < 3; ++kd) {
        int dd = d + kd - 1;
        bool ok = (dd >= 0) && (dd < DD);
        #pragma unroll
        for (int cc = 0; cc < CI_OUT; ++cc)
            r[cc * 3 + kd] = ok ? yb[(size_t)cc * NN + dd * NHW + tid] : 0.f;
    }
    for (int i = tid; i < CI_OUT * 3 * XPLANE; i += 256) yl[i] = 0.f;
    __syncthreads();
    #pragma unroll
    for (int j = 0; j < CI_OUT * 3; ++j)
        yl[j * XPLANE + wr] = r[j];
    __syncthreads();

    float a0 = 0.f, a1 = 0.f, a2 = 0.f, a3 = 0.f;

    for (int cc = 0; cc < CI_OUT; ++cc) {
        int ci = ci0 + cc;
        const float* w0 = wa + ((size_t)(co0 + 0) * CQ + ci) * 27;
        const float* w1 = wa + ((size_t)(co0 + 1) * CQ + ci) * 27;
        const float* w2 = wa + ((size_t)(co0 + 2) * CQ + ci) * 27;
        const float* w3 = wa + ((size_t)(co0 + 3) * CQ + ci) * 27;
        const float* yp = yl + cc * 3 * XPLANE + rb;
        #pragma unroll
        for (int kd = 0; kd < 3; ++kd) {
            int dd = d + kd - 1;
            if (dd < 0 || dd >= DD) continue;   // block-uniform
            #pragma unroll
            for (int kh = 0; kh < 3; ++kh) {
                #pragma unroll
                for (int kw = 0; kw < 3; ++kw) {
                    float yv = yp[kd * XPLANE + kh * 18 + kw];
                    int t = kd * 9 + kh * 3 + kw;
                    a0 = fmaf(yv, w0[t], a0);
                    a1 = fmaf(yv, w1[t], a1);
                    a2 = fmaf(yv, w2[t], a2);
                    a3 = fmaf(yv, w3[t], a3);
                }
            }
        }
    }

    size_t o = ((size_t)b * COUT + co0) * NN + d * NHW + tid;
    unsafeAtomicAdd(&out[o],          a0);
    unsafeAtomicAdd(&out[o + NN],     a1);
    unsafeAtomicAdd(&out[o + 2 * NN], a2);
    unsafeAtomicAdd(&out[o + 3 * NN], a3);
}

extern "C" void kernel_launch(void* const* d_in, const int* in_sizes, int n_in,
                              void* d_out, int out_size, void* d_ws, size_t ws_size,
                              hipStream_t stream) {
    const float* x  = (const float*)d_in[0];
    const float* wk = (const float*)d_in[1];
    const float* bk = (const float*)d_in[2];
    const float* wq = (const float*)d_in[3];
    const float* bq = (const float*)d_in[4];
    const float* wv = (const float*)d_in[5];
    const float* bv = (const float*)d_in[6];
    const float* wa = (const float*)d_in[7];
    const float* ba = (const float*)d_in[8];
    float* out = (float*)d_out;

    float* ws   = (float*)d_ws;
    float* kbuf = ws;                        // [2][32][2048]   131072
    float* qbuf = kbuf + BB * CQ * NN;       // [2][32][2048]   131072
    float* vbuf = qbuf + BB * CQ * NN;       // [2][32][2048]   131072
    float* zbuf = vbuf + BB * CQ * NN;       // [32][2048]      65536
    float* ybuf = zbuf + CQ * NN;            // [32][2048][2]   131072
    float* mqb  = ybuf + BB * CQ * NN;       // [2][32]         64

    init_kernel<<<2304, 256, 0, stream>>>(bk, bq, bv, ba, x, kbuf, qbuf, vbuf, out, zbuf, ybuf);
    conv_qkv_kernel<<<512, 256, 0, stream>>>(x, wk, wq, wv, kbuf, qbuf, vbuf);
    qmax_kernel<<<64, 256, 0, stream>>>(qbuf, mqb);
    mz_partial_kernel<<<1024, 256, 0, stream>>>(kbuf, qbuf, mqb, zbuf);
    att_partial_kernel<<<1024, 256, 0, stream>>>(kbuf, qbuf, vbuf, mqb, zbuf, ybuf);
    conv_out_kernel<<<1024, 256, 0, stream>>>(ybuf, wa, out);
}

// Round 10
// 90.310 us; speedup vs baseline: 1.4026x; 1.0699x over previous
//
#include <hip/hip_runtime.h>

#define BB 2
#define CIN 64
#define CQ 32
#define DD 8
#define HH 16
#define WWW 16
#define NN 2048   // D*H*W
#define NHW 256   // H*W
#define COUT 64

#define XPLANE 324          // 18*18 padded plane (conv_out)
#define CI_OUT 8            // ci per block (out conv) -- single stage

// conv_qkv spatial-quad geometry
#define QROWS 18
#define QCOLS 20
#define QPLANE (QROWS * QCOLS)   // 360 floats
#define QCI 4               // ci per staging phase

#define LOG2E 1.44269504088896340736f

__device__ __forceinline__ float fast_exp2(float x) {
#if __has_builtin(__builtin_amdgcn_exp2f)
    return __builtin_amdgcn_exp2f(x);    // single v_exp_f32
#else
    return exp2f(x);
#endif
}

// ---- init: qkv <- bias ; out <- x + bias ; zbuf,ybuf <- 0 ----
__global__ __launch_bounds__(256) void init_kernel(
    const float* __restrict__ bk, const float* __restrict__ bq, const float* __restrict__ bv,
    const float* __restrict__ ba, const float* __restrict__ x,
    float* __restrict__ kout, float* __restrict__ qout, float* __restrict__ vout,
    float* __restrict__ out, float* __restrict__ zbuf, float* __restrict__ ybuf)
{
    int i = blockIdx.x * 256 + threadIdx.x;
    if (i < BB * CQ * NN) {
        int co = (i >> 11) & 31;
        kout[i] = bk[co];
        qout[i] = bq[co];
        vout[i] = bv[co];
    } else if (i < 3 * BB * CQ * NN) {
        int j = i - BB * CQ * NN;             // 0 .. 262143
        int co = (j >> 11) & 63;
        out[j] = x[j] + ba[co];
    } else if (i < 3 * BB * CQ * NN + CQ * NN) {
        zbuf[i - 3 * BB * CQ * NN] = 0.f;
    } else {
        ybuf[i - 3 * BB * CQ * NN - CQ * NN] = 0.f;
    }
}

// ---- fused k,q,v conv: grid 512 = 4cisplit(HIGH) x {2b,2dq,32co}(LOW) ----
// Lane map for compute reads: h = lane&15, wqi = lane>>4. A lane octet then has
// 8 consecutive h at fixed wqi; b128 window start bank-group (5h+wqi)%8 takes
// all 8 values (5 coprime 8) -> octet tiles all 32 banks exactly once ->
// conflict-free (r9 had h=lane>>2: 8-way same-bank different-address collisions,
// 8.45M SQ_LDS_BANK_CONFLICT, LDS pipe was the critical path).
__global__ __launch_bounds__(256, 2) void conv_qkv_kernel(
    const float* __restrict__ x,
    const float* __restrict__ wk, const float* __restrict__ wq, const float* __restrict__ wv,
    float* __restrict__ kout, float* __restrict__ qout, float* __restrict__ vout)
{
    int bid   = blockIdx.x;
    int split = bid >> 7;          // HIGH bits: split partners share bid%8 -> same XCD
    int inner = bid & 127;
    int co    = inner & 31;
    int dq    = (inner >> 5) & 1;
    int b     = inner >> 6;
    int ci0   = split << 4;        // 16 ci per split
    int d0    = dq << 2;           // output planes d0 .. d0+3

    __shared__ float xl[QCI * 6 * QPLANE];   // 34560 B
    __shared__ float tl[3 * 1024];           // 12 KB epilogue transpose buffer

    int tid = threadIdx.x;
    int hw = tid >> 4;
    int ww = tid & 15;
    int wr = (hw + 1) * QCOLS + (ww + 1);
    int pn  = tid >> 6;            // 0..3 d-plane (wave id)
    int rem = tid & 63;
    int h   = rem & 15;            // 0..15  (bank-conflict-free map)
    int wqi = rem >> 4;            // 0..3

    const float* xb = x + ((size_t)b * CIN + ci0) * NN;

    float r[QCI * 6];
    #pragma unroll
    for (int p = 0; p < 6; ++p) {
        int dd = d0 - 1 + p;
        if (dd >= 0 && dd < DD) {              // block-uniform
            #pragma unroll
            for (int cl = 0; cl < QCI; ++cl)
                r[cl * 6 + p] = xb[(size_t)cl * NN + dd * NHW + tid];
        }
    }
    for (int i = tid; i < QCI * 6 * QPLANE; i += 256) xl[i] = 0.f;
    __syncthreads();
    #pragma unroll
    for (int p = 0; p < 6; ++p) {
        int dd = d0 - 1 + p;
        if (dd >= 0 && dd < DD) {
            #pragma unroll
            for (int cl = 0; cl < QCI; ++cl)
                xl[cl * 6 * QPLANE + p * QPLANE + wr] = r[cl * 6 + p];
        }
    }

    float acc[3][4];
    #pragma unroll
    for (int s = 0; s < 3; ++s)
        #pragma unroll
        for (int o = 0; o < 4; ++o) acc[s][o] = 0.f;

    #pragma unroll 1
    for (int ph = 0; ph < 4; ++ph) {
        __syncthreads();
        if (ph < 3) {
            #pragma unroll
            for (int p = 0; p < 6; ++p) {
                int dd = d0 - 1 + p;
                if (dd >= 0 && dd < DD) {
                    #pragma unroll
                    for (int cl = 0; cl < QCI; ++cl)
                        r[cl * 6 + p] = xb[(size_t)((ph + 1) * QCI + cl) * NN + dd * NHW + tid];
                }
            }
        }

        #pragma unroll 1
        for (int cl = 0; cl < QCI; ++cl) {
            int ci = ci0 + ph * QCI + cl;
            const float* wk0 = wk + ((size_t)co * CIN + ci) * 27;
            const float* wq0 = wq + ((size_t)co * CIN + ci) * 27;
            const float* wv0 = wv + ((size_t)co * CIN + ci) * 27;
            const float* xp  = xl + cl * 6 * QPLANE + pn * QPLANE + h * QCOLS + wqi * 4;

            #pragma unroll
            for (int kd = 0; kd < 3; ++kd) {
                float ws[3][9];
                #pragma unroll
                for (int j = 0; j < 9; ++j) {
                    int t = kd * 9 + j;
                    ws[0][j] = wk0[t]; ws[1][j] = wq0[t]; ws[2][j] = wv0[t];
                }
                #pragma unroll
                for (int kh = 0; kh < 3; ++kh) {
                    const float* xr = xp + kd * QPLANE + kh * QCOLS;
                    float4 xa  = *(const float4*)xr;
                    float2 xb2 = *(const float2*)(xr + 4);
                    float xw[6] = {xa.x, xa.y, xa.z, xa.w, xb2.x, xb2.y};
                    #pragma unroll
                    for (int kw = 0; kw < 3; ++kw) {
                        int t = kh * 3 + kw;
                        #pragma unroll
                        for (int o = 0; o < 4; ++o) {
                            float xv = xw[o + kw];
                            acc[0][o] = fmaf(ws[0][t], xv, acc[0][o]);
                            acc[1][o] = fmaf(ws[1][t], xv, acc[1][o]);
                            acc[2][o] = fmaf(ws[2][t], xv, acc[2][o]);
                        }
                    }
                }
            }
        }

        __syncthreads();
        if (ph < 3) {
            #pragma unroll
            for (int p = 0; p < 6; ++p) {
                int dd = d0 - 1 + p;
                if (dd >= 0 && dd < DD) {
                    #pragma unroll
                    for (int cl = 0; cl < QCI; ++cl)
                        xl[cl * 6 * QPLANE + p * QPLANE + wr] = r[cl * 6 + p];
                }
            }
        }
    }

    // ---- epilogue: one LDS transpose (all 3 sets) -> contiguous atomic lanes ----
    // wloc formula is lane-map-independent: (pn,h,wqi) -> slot pn*256 + h*16 + wqi*4
    size_t base = ((size_t)b * CQ + co) * NN + d0 * NHW;
    int wloc = pn * 256 + h * 16 + wqi * 4;
    __syncthreads();
    {
        float4 f0; f0.x = acc[0][0]; f0.y = acc[0][1]; f0.z = acc[0][2]; f0.w = acc[0][3];
        float4 f1; f1.x = acc[1][0]; f1.y = acc[1][1]; f1.z = acc[1][2]; f1.w = acc[1][3];
        float4 f2; f2.x = acc[2][0]; f2.y = acc[2][1]; f2.z = acc[2][2]; f2.w = acc[2][3];
        *(float4*)&tl[wloc]        = f0;
        *(float4*)&tl[1024 + wloc] = f1;
        *(float4*)&tl[2048 + wloc] = f2;
    }
    __syncthreads();
    #pragma unroll
    for (int p = 0; p < 4; ++p) {
        unsafeAtomicAdd(&kout[base + p * NHW + tid], tl[p * 256 + tid]);
        unsafeAtomicAdd(&qout[base + p * NHW + tid], tl[1024 + p * 256 + tid]);
        unsafeAtomicAdd(&vout[base + p * NHW + tid], tl[2048 + p * 256 + tid]);
    }
}

// ---- per-(b,c) row max|q|: grid 64 x 256 ----
__global__ __launch_bounds__(256) void qmax_kernel(
    const float* __restrict__ qbuf, float* __restrict__ mq)
{
    int row = blockIdx.x;
    int tid = threadIdx.x;
    const float4* q = (const float4*)(qbuf + (size_t)row * NN);
    float4 v0 = q[tid], v1 = q[tid + 256];
    float mx = fmaxf(fmaxf(fmaxf(fabsf(v0.x), fabsf(v0.y)), fmaxf(fabsf(v0.z), fabsf(v0.w))),
                     fmaxf(fmaxf(fabsf(v1.x), fabsf(v1.y)), fmaxf(fabsf(v1.z), fabsf(v1.w))));
    #pragma unroll
    for (int off = 32; off; off >>= 1)
        mx = fmaxf(mx, __shfl_down(mx, off, 64));
    __shared__ float red[4];
    if ((tid & 63) == 0) red[tid >> 6] = mx;
    __syncthreads();
    if (tid == 0) mq[row] = fmaxf(fmaxf(red[0], red[1]), fmaxf(red[2], red[3]));
}

// ---- softmax denominators with upper-bound shift: grid 1024 ----
__global__ __launch_bounds__(256) void mz_partial_kernel(
    const float* __restrict__ kbuf, const float* __restrict__ qbuf,
    const float* __restrict__ mq, float* __restrict__ zbuf)
{
    int bid = blockIdx.x;
    int nchunk = bid >> 7;
    int c      = (bid >> 2) & 31;
    int mtile  = bid & 3;

    __shared__ float q0l[256], q1l[256];
    int tid = threadIdx.x;
    int n0 = nchunk * 256;
    if (tid < 64) {
        float4 v = ((const float4*)(qbuf + (size_t)c * NN + n0))[tid];
        v.x *= LOG2E; v.y *= LOG2E; v.z *= LOG2E; v.w *= LOG2E;
        ((float4*)q0l)[tid] = v;
    } else if (tid < 128) {
        float4 v = ((const float4*)(qbuf + (size_t)(CQ + c) * NN + n0))[tid - 64];
        v.x *= LOG2E; v.y *= LOG2E; v.z *= LOG2E; v.w *= LOG2E;
        ((float4*)q1l)[tid - 64] = v;
    }
    __syncthreads();

    int m = mtile * 512 + tid * 2;
    float2 k0 = *(const float2*)(kbuf + (size_t)c * NN + m);
    float2 k1 = *(const float2*)(kbuf + (size_t)(CQ + c) * NN + m);
    float mq0 = mq[c], mq1 = mq[CQ + c];

    float nma = -LOG2E * fmaf(fabsf(k0.x), mq0, fabsf(k1.x) * mq1);
    float nmb = -LOG2E * fmaf(fabsf(k0.y), mq0, fabsf(k1.y) * mq1);

    const float4* q0v = (const float4*)q0l;
    const float4* q1v = (const float4*)q1l;

    float za = 0.f, zb = 0.f;
    #pragma unroll 4
    for (int i = 0; i < 64; ++i) {
        float4 a = q0v[i], b4 = q1v[i];
        za += fast_exp2(fmaf(k0.x, a.x, fmaf(k1.x, b4.x, nma)))
            + fast_exp2(fmaf(k0.x, a.y, fmaf(k1.x, b4.y, nma)))
            + fast_exp2(fmaf(k0.x, a.z, fmaf(k1.x, b4.z, nma)))
            + fast_exp2(fmaf(k0.x, a.w, fmaf(k1.x, b4.w, nma)));
        zb += fast_exp2(fmaf(k0.y, a.x, fmaf(k1.y, b4.x, nmb)))
            + fast_exp2(fmaf(k0.y, a.y, fmaf(k1.y, b4.y, nmb)))
            + fast_exp2(fmaf(k0.y, a.z, fmaf(k1.y, b4.z, nmb)))
            + fast_exp2(fmaf(k0.y, a.w, fmaf(k1.y, b4.w, nmb)));
    }
    unsafeAtomicAdd(&zbuf[(size_t)c * NN + m],     za);
    unsafeAtomicAdd(&zbuf[(size_t)c * NN + m + 1], zb);
}

// ---- attention apply, accumulating directly into ybuf: grid 1024 ----
__global__ __launch_bounds__(256) void att_partial_kernel(
    const float* __restrict__ kbuf, const float* __restrict__ qbuf,
    const float* __restrict__ vbuf,
    const float* __restrict__ mq, const float* __restrict__ zbuf,
    float* __restrict__ ybuf)
{
    int bid = blockIdx.x;
    int mchunk = bid >> 7;
    int c      = (bid >> 2) & 31;
    int ntile  = bid & 3;

    __shared__ float k0l[256], k1l[256], vz0l[256], vz1l[256], nMl[256];
    int tid = threadIdx.x;
    {
        int m = mchunk * 256 + tid;
        float k0 = kbuf[(size_t)c * NN + m];
        float k1 = kbuf[(size_t)(CQ + c) * NN + m];
        float mq0 = mq[c], mq1 = mq[CQ + c];
        float rz = 1.f / zbuf[(size_t)c * NN + m];
        k0l[tid]  = k0;
        k1l[tid]  = k1;
        vz0l[tid] = vbuf[(size_t)c * NN + m] * rz;
        vz1l[tid] = vbuf[(size_t)(CQ + c) * NN + m] * rz;
        nMl[tid]  = -LOG2E * fmaf(fabsf(k0), mq0, fabsf(k1) * mq1);
    }
    __syncthreads();

    int n = ntile * 512 + tid * 2;
    float2 q0 = *(const float2*)(qbuf + (size_t)c * NN + n);
    float2 q1 = *(const float2*)(qbuf + (size_t)(CQ + c) * NN + n);
    q0.x *= LOG2E; q0.y *= LOG2E;
    q1.x *= LOG2E; q1.y *= LOG2E;

    const float4* k0v = (const float4*)k0l;
    const float4* k1v = (const float4*)k1l;
    const float4* v0v = (const float4*)vz0l;
    const float4* v1v = (const float4*)vz1l;
    const float4* nMv = (const float4*)nMl;

    float a00 = 0.f, a01 = 0.f;   // b=0: n, n+1
    float a10 = 0.f, a11 = 0.f;   // b=1

    #pragma unroll 2
    for (int i = 0; i < 64; ++i) {
        float4 kk0 = k0v[i], kk1 = k1v[i], w0 = v0v[i], w1 = v1v[i], nm = nMv[i];
        #define ATTS(KX,K1X,W0X,W1X,NMX) { \
            float e0 = fast_exp2(fmaf(q0.x, KX, fmaf(q1.x, K1X, NMX))); \
            float e1 = fast_exp2(fmaf(q0.y, KX, fmaf(q1.y, K1X, NMX))); \
            a00 = fmaf(e0, W0X, a00); a10 = fmaf(e0, W1X, a10); \
            a01 = fmaf(e1, W0X, a01); a11 = fmaf(e1, W1X, a11); }
        ATTS(kk0.x, kk1.x, w0.x, w1.x, nm.x)
        ATTS(kk0.y, kk1.y, w0.y, w1.y, nm.y)
        ATTS(kk0.z, kk1.z, w0.z, w1.z, nm.z)
        ATTS(kk0.w, kk1.w, w0.w, w1.w, nm.w)
        #undef ATTS
    }

    size_t base = ((size_t)c * NN + n) * BB;   // ybuf flat [c][n][b]
    unsafeAtomicAdd(&ybuf[base + 0], a00);
    unsafeAtomicAdd(&ybuf[base + 1], a10);
    unsafeAtomicAdd(&ybuf[base + 2], a01);
    unsafeAtomicAdd(&ybuf[base + 3], a11);
}

// ---- final conv (32->64): grid 2b*8d*16cog*4cisplit = 1024 blocks ----
__global__ __launch_bounds__(256, 4) void conv_out_kernel(
    const float* __restrict__ ybuf,
    const float* __restrict__ wa,
    float* __restrict__ out)
{
    int bid   = blockIdx.x;
    int split = bid & 3;
    int cog   = (bid >> 2) & 15;
    int d     = (bid >> 6) & 7;
    int b     = bid >> 9;
    int co0   = cog << 2;
    int ci0   = split << 3;   // 8 ci per split

    __shared__ float yl[CI_OUT * 3 * XPLANE];   // 31104 B

    int tid = threadIdx.x;
    int h  = tid >> 4;
    int w  = tid & 15;
    int wr = (h + 1) * 18 + (w + 1);
    int rb = h * 18 + w;

    const float* yb = ybuf + ((size_t)b * CQ + ci0) * NN;   // [C,N,B] flat as [B][32][2048]

    float r[CI_OUT * 3];
    #pragma unroll
    for (int kd = 0; kd < 3; ++kd) {
        int dd = d + kd - 1;
        bool ok = (dd >= 0) && (dd < DD);
        #pragma unroll
        for (int cc = 0; cc < CI_OUT; ++cc)
            r[cc * 3 + kd] = ok ? yb[(size_t)cc * NN + dd * NHW + tid] : 0.f;
    }
    for (int i = tid; i < CI_OUT * 3 * XPLANE; i += 256) yl[i] = 0.f;
    __syncthreads();
    #pragma unroll
    for (int j = 0; j < CI_OUT * 3; ++j)
        yl[j * XPLANE + wr] = r[j];
    __syncthreads();

    float a0 = 0.f, a1 = 0.f, a2 = 0.f, a3 = 0.f;

    for (int cc = 0; cc < CI_OUT; ++cc) {
        int ci = ci0 + cc;
        const float* w0 = wa + ((size_t)(co0 + 0) * CQ + ci) * 27;
        const float* w1 = wa + ((size_t)(co0 + 1) * CQ + ci) * 27;
        const float* w2 = wa + ((size_t)(co0 + 2) * CQ + ci) * 27;
        const float* w3 = wa + ((size_t)(co0 + 3) * CQ + ci) * 27;
        const float* yp = yl + cc * 3 * XPLANE + rb;
        #pragma unroll
        for (int kd = 0; kd < 3; ++kd) {
            int dd = d + kd - 1;
            if (dd < 0 || dd >= DD) continue;   // block-uniform
            #pragma unroll
            for (int kh = 0; kh < 3; ++kh) {
                #pragma unroll
                for (int kw = 0; kw < 3; ++kw) {
                    float yv = yp[kd * XPLANE + kh * 18 + kw];
                    int t = kd * 9 + kh * 3 + kw;
                    a0 = fmaf(yv, w0[t], a0);
                    a1 = fmaf(yv, w1[t], a1);
                    a2 = fmaf(yv, w2[t], a2);
                    a3 = fmaf(yv, w3[t], a3);
                }
            }
        }
    }

    size_t o = ((size_t)b * COUT + co0) * NN + d * NHW + tid;
    unsafeAtomicAdd(&out[o],          a0);
    unsafeAtomicAdd(&out[o + NN],     a1);
    unsafeAtomicAdd(&out[o + 2 * NN], a2);
    unsafeAtomicAdd(&out[o + 3 * NN], a3);
}

extern "C" void kernel_launch(void* const* d_in, const int* in_sizes, int n_in,
                              void* d_out, int out_size, void* d_ws, size_t ws_size,
                              hipStream_t stream) {
    const float* x  = (const float*)d_in[0];
    const float* wk = (const float*)d_in[1];
    const float* bk = (const float*)d_in[2];
    const float* wq = (const float*)d_in[3];
    const float* bq = (const float*)d_in[4];
    const float* wv = (const float*)d_in[5];
    const float* bv = (const float*)d_in[6];
    const float* wa = (const float*)d_in[7];
    const float* ba = (const float*)d_in[8];
    float* out = (float*)d_out;

    float* ws   = (float*)d_ws;
    float* kbuf = ws;                        // [2][32][2048]   131072
    float* qbuf = kbuf + BB * CQ * NN;       // [2][32][2048]   131072
    float* vbuf = qbuf + BB * CQ * NN;       // [2][32][2048]   131072
    float* zbuf = vbuf + BB * CQ * NN;       // [32][2048]      65536
    float* ybuf = zbuf + CQ * NN;            // [32][2048][2]   131072
    float* mqb  = ybuf + BB * CQ * NN;       // [2][32]         64

    init_kernel<<<2304, 256, 0, stream>>>(bk, bq, bv, ba, x, kbuf, qbuf, vbuf, out, zbuf, ybuf);
    conv_qkv_kernel<<<512, 256, 0, stream>>>(x, wk, wq, wv, kbuf, qbuf, vbuf);
    qmax_kernel<<<64, 256, 0, stream>>>(qbuf, mqb);
    mz_partial_kernel<<<1024, 256, 0, stream>>>(kbuf, qbuf, mqb, zbuf);
    att_partial_kernel<<<1024, 256, 0, stream>>>(kbuf, qbuf, vbuf, mqb, zbuf, ybuf);
    conv_out_kernel<<<1024, 256, 0, stream>>>(ybuf, wa, out);
}